// Round 1
// baseline (42.429 us; speedup 1.0000x reference)
//
#include <hip/hip_runtime.h>

// GraphAttentionPooling: B=196608 rows x F=256 fp32, P=3 rows per group,
// G=65536 groups. out[g,f] = sum_p softmax_p(x[g,p,:]·w + b) * x[g,p,f].
// One 64-lane wave per group; lane i owns columns 4i..4i+3 (float4).

#define GAP_F 256
#define GAP_P 3

__global__ __launch_bounds__(256) void gap_fused_kernel(
    const float* __restrict__ x,      // [G*3, 256]
    const float* __restrict__ w,      // [1, 256]
    const float* __restrict__ bias,   // [1]
    float* __restrict__ out,          // [G, 256]
    int G)
{
    const int gwave = (int)((blockIdx.x * (unsigned)blockDim.x + threadIdx.x) >> 6);
    const int lane  = threadIdx.x & 63;
    if (gwave >= G) return;

    // weight fragment: lane i holds w[4i..4i+3] (1 KB total, L1/L2 resident)
    const float4 w4 = reinterpret_cast<const float4*>(w)[lane];

    const float4* __restrict__ xrow =
        reinterpret_cast<const float4*>(x + (size_t)gwave * (GAP_P * GAP_F));

    // three rows of the group, 16 B per lane, fully coalesced (1 KB/wave/load)
    const float4 x0 = xrow[lane];
    const float4 x1 = xrow[64 + lane];
    const float4 x2 = xrow[128 + lane];

    // per-lane partial dot products
    float s0 = x0.x * w4.x + x0.y * w4.y + x0.z * w4.z + x0.w * w4.w;
    float s1 = x1.x * w4.x + x1.y * w4.y + x1.z * w4.z + x1.w * w4.w;
    float s2 = x2.x * w4.x + x2.y * w4.y + x2.z * w4.z + x2.w * w4.w;

    // 64-lane butterfly reduction (wave64: 6 steps)
    #pragma unroll
    for (int off = 32; off >= 1; off >>= 1) {
        s0 += __shfl_xor(s0, off, 64);
        s1 += __shfl_xor(s1, off, 64);
        s2 += __shfl_xor(s2, off, 64);
    }

    const float b = bias[0];
    s0 += b; s1 += b; s2 += b;

    // 3-way softmax, computed redundantly in every lane (registers only)
    const float m  = fmaxf(fmaxf(s0, s1), s2);
    const float e0 = __expf(s0 - m);
    const float e1 = __expf(s1 - m);
    const float e2 = __expf(s2 - m);
    const float inv = 1.0f / (e0 + e1 + e2);
    const float a0 = e0 * inv, a1 = e1 * inv, a2 = e2 * inv;

    float4 o;
    o.x = x0.x * a0 + x1.x * a1 + x2.x * a2;
    o.y = x0.y * a0 + x1.y * a1 + x2.y * a2;
    o.z = x0.z * a0 + x1.z * a1 + x2.z * a2;
    o.w = x0.w * a0 + x1.w * a1 + x2.w * a2;

    reinterpret_cast<float4*>(out + (size_t)gwave * GAP_F)[lane] = o;
}

extern "C" void kernel_launch(void* const* d_in, const int* in_sizes, int n_in,
                              void* d_out, int out_size, void* d_ws, size_t ws_size,
                              hipStream_t stream)
{
    const float* batch_rep = (const float*)d_in[0];   // [196608, 256]
    const float* W_weight  = (const float*)d_in[1];   // [1, 256]
    const float* W_bias    = (const float*)d_in[2];   // [1]
    float* out             = (float*)d_out;           // [G, 256, 1] flat

    const int B = in_sizes[0] / GAP_F;   // 196608
    const int G = B / GAP_P;             // 65536

    // 4 waves per 256-thread block, one wave per group
    const int waves_per_block = 256 / 64;
    const int grid = (G + waves_per_block - 1) / waves_per_block;

    gap_fused_kernel<<<grid, 256, 0, stream>>>(batch_rep, W_weight, W_bias, out, G);
}